// Round 2
// baseline (441.155 us; speedup 1.0000x reference)
//
#include <hip/hip_runtime.h>

typedef float floatx4 __attribute__((ext_vector_type(4)));
typedef __bf16 bf16x8 __attribute__((ext_vector_type(8)));
typedef unsigned short u16t;
typedef unsigned int u32t;

static __device__ __forceinline__ u16t f2bf(float f) {
  u32t u = __float_as_uint(f);
  u += 0x7FFFu + ((u >> 16) & 1u);   // RNE to bf16
  return (u16t)(u >> 16);
}
static __device__ __forceinline__ float bf2f(u16t h) {
  return __uint_as_float((u32t)h << 16);
}

#define MFMA(A, B, C) __builtin_amdgcn_mfma_f32_16x16x32_bf16((A), (B), (C), 0, 0, 0)

// Pre-pack w_qkv [128][384] and w_out [128][128] (fp32 row-major) into bf16
// MFMA B-fragment order: [(ntile*4 + kstep)*64 + lane]*8 + j  =
//   W[32*kstep + (lane>>4)*8 + j][16*ntile + (lane&15)]
__global__ void pack_weights_kernel(const float* __restrict__ wqkv,
                                    const float* __restrict__ wout,
                                    u16t* __restrict__ wq_p,
                                    u16t* __restrict__ wo_p) {
  int g = blockIdx.x * blockDim.x + threadIdx.x;  // 0..8191
  int l = g & 63;
  int s = (g >> 6) & 3;
  int n = g >> 8;  // 0..31 : 0..23 -> w_qkv ntiles, 24..31 -> w_out ntiles
  int kbase = 32 * s + ((l >> 4) * 8);
  int cl = l & 15;
  if (n < 24) {
    int col = 16 * n + cl;
    u16t* dst = wq_p + g * 8;
#pragma unroll
    for (int j = 0; j < 8; ++j) dst[j] = f2bf(wqkv[(kbase + j) * 384 + col]);
  } else {
    int col = 16 * (n - 24) + cl;
    u16t* dst = wo_p + (g - 24 * 256) * 8;
#pragma unroll
    for (int j = 0; j < 8; ++j) dst[j] = f2bf(wout[(kbase + j) * 128 + col]);
  }
}

// One workgroup per window (4096 windows). 256 threads = 4 waves.
// Wave w owns query-row tile m = w (rows 16w..16w+15) through the whole pipe.
__global__ __launch_bounds__(256, 2) void win_attn_kernel(
    const float* __restrict__ x, const float* __restrict__ gamma,
    const float* __restrict__ beta, const u16t* __restrict__ wq_p,
    const float* __restrict__ bqkv, const u16t* __restrict__ wo_p,
    const float* __restrict__ bout, float* __restrict__ out) {
  // xn: cols 0..127 = hi(LN(x)), cols 128..255 = lo residual (split bf16)
  __shared__ u16t xn[64][264];
  // qs/ks: cols 0..15 = hi, cols 16..31 = lo residual
  __shared__ u16t qs[64][40];
  __shared__ u16t ks[64][40];
  __shared__ u16t vt[16][72];   // V^T: [channel][token]
  __shared__ u16t ps[64][72];   // P (probs) bf16, [query][key 0..63]
  __shared__ u16t at[64][136];  // attention output, [token][C]

  const int tid = threadIdx.x;
  const int lane = tid & 63;
  const int w = tid >> 6;       // wave id = m-tile
  const int llo = lane & 15;
  const int lhi = lane >> 4;

  const int wi = blockIdx.x;
  const int bimg = wi >> 6;
  const int widx = wi & 63;
  const int nwh = widx >> 3;
  const int nww = widx & 7;
  const int base_off = (((bimg * 56) + nwh * 7) * 56 + nww * 7) * 128;
  const float* xbase = x + base_off;

  // zero xn pad rows (tokens 49..63), both hi and lo halves
  for (int i = tid; i < 15 * 128; i += 256) {
    int r = i >> 7, c = (i & 127) << 1;
    *(u32t*)&xn[49 + r][c] = 0;
  }

  // ---- LayerNorm -> split bf16 (hi+lo) in LDS. One wave per token. ----
  {
    const float g0 = gamma[2 * lane], g1 = gamma[2 * lane + 1];
    const float b0 = beta[2 * lane], b1 = beta[2 * lane + 1];
    for (int t = w; t < 49; t += 4) {
      int wr = t / 7, wc = t - wr * 7;
      const float* row = xbase + (wr * 56 + wc) * 128;
      float2 v = *(const float2*)(row + 2 * lane);
      float sm = v.x + v.y;
      float sq = v.x * v.x + v.y * v.y;
#pragma unroll
      for (int m = 1; m < 64; m <<= 1) {
        sm += __shfl_xor(sm, m);
        sq += __shfl_xor(sq, m);
      }
      float mean = sm * (1.f / 128.f);
      float var = sq * (1.f / 128.f) - mean * mean;
      float rs = rsqrtf(var + 1e-5f);
      float y0 = (v.x - mean) * rs * g0 + b0;
      float y1 = (v.y - mean) * rs * g1 + b1;
      u16t h0 = f2bf(y0), h1 = f2bf(y1);
      u16t l0 = f2bf(y0 - bf2f(h0)), l1 = f2bf(y1 - bf2f(h1));
      *(u32t*)&xn[t][2 * lane] = (u32t)h0 | ((u32t)h1 << 16);
      *(u32t*)&xn[t][128 + 2 * lane] = (u32t)l0 | ((u32t)l1 << 16);
    }
  }
  __syncthreads();

  const int rowA = 16 * w + llo;      // A-frag row (m = lane&15)
  const int rowC = 16 * w + lhi * 4;  // C-frag row base (row = quad*4+reg)
  const float SEXP = 0.25f * 1.44269504088896340736f;  // SCALE * log2(e)
  const floatx4 z4 = {0.f, 0.f, 0.f, 0.f};

  float rsum[4];
#pragma unroll 1
  for (int h = 0; h < 8; ++h) {
    // ---- QKV projection for head h: (x_hi + x_lo) @ W, fp32-accurate x ----
    floatx4 aq = z4, ak = z4, av = z4;
    const u16t* pwq = wq_p + ((h * 4) * 64 + lane) * 8;
    const u16t* pwk = wq_p + (((8 + h) * 4) * 64 + lane) * 8;
    const u16t* pwv = wq_p + (((16 + h) * 4) * 64 + lane) * 8;
#pragma unroll
    for (int s = 0; s < 4; ++s) {
      bf16x8 ah = *(const bf16x8*)&xn[rowA][s * 32 + lhi * 8];
      bf16x8 al = *(const bf16x8*)&xn[rowA][128 + s * 32 + lhi * 8];
      bf16x8 bq = *(const bf16x8*)(pwq + s * 512);
      bf16x8 bk = *(const bf16x8*)(pwk + s * 512);
      bf16x8 bv = *(const bf16x8*)(pwv + s * 512);
      aq = MFMA(ah, bq, aq);
      aq = MFMA(al, bq, aq);
      ak = MFMA(ah, bk, ak);
      ak = MFMA(al, bk, ak);
      av = MFMA(ah, bv, av);
      av = MFMA(al, bv, av);
    }
    {
      float bq = bqkv[h * 16 + llo];
      float bk = bqkv[128 + h * 16 + llo];
      float bv = bqkv[256 + h * 16 + llo];
#pragma unroll
      for (int r = 0; r < 4; ++r) {
        float qv = aq[r] + bq;
        float kv = ak[r] + bk;
        u16t qh = f2bf(qv), kh = f2bf(kv);
        qs[rowC + r][llo] = qh;
        qs[rowC + r][16 + llo] = f2bf(qv - bf2f(qh));
        ks[rowC + r][llo] = kh;
        ks[rowC + r][16 + llo] = f2bf(kv - bf2f(kh));
      }
      ushort4 vv;
      vv.x = f2bf(av[0] + bv);
      vv.y = f2bf(av[1] + bv);
      vv.z = f2bf(av[2] + bv);
      vv.w = f2bf(av[3] + bv);
      *(ushort4*)&vt[llo][rowC] = vv;  // V transposed: vt[ch][token]
    }
    __syncthreads();

    // ---- scores = q @ k^T, split-precision: A=[q_hi|q_lo],
    //      B1=[k_hi|k_hi], B2=[k_lo|k_lo] -> exact fp32-precision q.k ----
    floatx4 sc[4];
    {
      bf16x8 a = *(const bf16x8*)&qs[rowA][lhi * 8];
      const int bcol = (lhi & 1) * 8;
#pragma unroll
      for (int n = 0; n < 4; ++n) {
        bf16x8 b1 = *(const bf16x8*)&ks[16 * n + llo][bcol];
        bf16x8 b2 = *(const bf16x8*)&ks[16 * n + llo][16 + bcol];
        sc[n] = MFMA(a, b2, MFMA(a, b1, z4));
      }
    }

    // ---- in-register softmax over key dim (cols >=49 masked) ----
#pragma unroll
    for (int j = 0; j < 4; ++j) {
      float m0 = -3.0e38f;
#pragma unroll
      for (int n = 0; n < 4; ++n) {
        int c = 16 * n + llo;
        if (c < 49) m0 = fmaxf(m0, sc[n][j]);
      }
#pragma unroll
      for (int m = 1; m < 16; m <<= 1) m0 = fmaxf(m0, __shfl_xor(m0, m));
      float s0 = 0.f;
#pragma unroll
      for (int n = 0; n < 4; ++n) {
        int c = 16 * n + llo;
        float p = (c < 49) ? exp2f((sc[n][j] - m0) * SEXP) : 0.f;
        sc[n][j] = p;
        s0 += p;
      }
#pragma unroll
      for (int m = 1; m < 16; m <<= 1) s0 += __shfl_xor(s0, m);
      rsum[j] = 1.f / s0;  // defer normalization to PV epilogue
    }
    // P: C-layout -> LDS -> A-layout (intra-wave only: rows 16w..16w+15)
#pragma unroll
    for (int n = 0; n < 4; ++n)
#pragma unroll
      for (int j = 0; j < 4; ++j)
        ps[rowC + j][16 * n + llo] = f2bf(sc[n][j]);
    __asm__ volatile("s_waitcnt lgkmcnt(0)" ::: "memory");

    // ---- attn = P @ V, normalize, write to at[token][h*16+ch] ----
    floatx4 ao = z4;
#pragma unroll
    for (int s = 0; s < 2; ++s) {
      bf16x8 a = *(const bf16x8*)&ps[rowA][s * 32 + lhi * 8];
      bf16x8 b = *(const bf16x8*)&vt[llo][s * 32 + lhi * 8];
      ao = MFMA(a, b, ao);
    }
#pragma unroll
    for (int r = 0; r < 4; ++r)
      at[rowC + r][h * 16 + llo] = f2bf(ao[r] * rsum[r]);
    __syncthreads();  // protects qs/ks/vt reuse next head (+ final at)
  }

  // ---- out projection [49,128] @ [128,128] + bias, merge-store ----
  floatx4 oc[8];
#pragma unroll
  for (int n = 0; n < 8; ++n) oc[n] = z4;
#pragma unroll
  for (int s = 0; s < 4; ++s) {
    bf16x8 a = *(const bf16x8*)&at[rowA][s * 32 + lhi * 8];
#pragma unroll
    for (int n = 0; n < 8; ++n)
      oc[n] = MFMA(a, *(const bf16x8*)(wo_p + ((n * 4 + s) * 64 + lane) * 8),
                   oc[n]);
  }
  float bo[8];
#pragma unroll
  for (int n = 0; n < 8; ++n) bo[n] = bout[16 * n + llo];
  float* obase = out + base_off;
#pragma unroll
  for (int r = 0; r < 4; ++r) {
    int t = rowC + r;
    if (t < 49) {
      int wr = t / 7, wc = t - wr * 7;
      float* orow = obase + (wr * 56 + wc) * 128;
#pragma unroll
      for (int n = 0; n < 8; ++n) orow[16 * n + llo] = oc[n][r] + bo[n];
    }
  }
}

extern "C" void kernel_launch(void* const* d_in, const int* in_sizes, int n_in,
                              void* d_out, int out_size, void* d_ws,
                              size_t ws_size, hipStream_t stream) {
  const float* x = (const float*)d_in[0];
  const float* ln_g = (const float*)d_in[1];
  const float* ln_b = (const float*)d_in[2];
  const float* w_qkv = (const float*)d_in[3];
  const float* b_qkv = (const float*)d_in[4];
  const float* w_out = (const float*)d_in[5];
  const float* b_out = (const float*)d_in[6];
  float* out = (float*)d_out;

  u16t* wq_p = (u16t*)d_ws;          // 24*4*64*8 = 49152 bf16 (96 KB)
  u16t* wo_p = wq_p + 24 * 256 * 8;  // 8*4*64*8 = 16384 bf16 (32 KB)

  hipLaunchKernelGGL(pack_weights_kernel, dim3(32), dim3(256), 0, stream,
                     w_qkv, w_out, wq_p, wo_p);
  hipLaunchKernelGGL(win_attn_kernel, dim3(4096), dim3(256), 0, stream, x,
                     ln_g, ln_b, wq_p, b_qkv, wo_p, b_out, out);
}